// Round 5
// baseline (2663.449 us; speedup 1.0000x reference)
//
#include <hip/hip_runtime.h>
#include <hip/hip_bf16.h>
#include <stdint.h>

// Problem constants (B=8, S=2048, H=4096)
#define M_TOTAL 16384
#define K_DIM   4096
#define N_DIM   4096
#define BM 128
#define BN 128
#define BK 32
#define NK (K_DIM / BK)   // 128 K-steps

typedef unsigned short u16;
typedef __attribute__((ext_vector_type(4))) float  f32x4;
typedef __attribute__((ext_vector_type(8))) short  bf16x8;   // 8 bf16 = 4 VGPRs (MFMA A/B frag)
typedef __attribute__((ext_vector_type(8))) unsigned short u16x8;

// ---- bf16 split helpers (round-to-nearest-even via bit trick) ----
__device__ __forceinline__ u16 f2bf_rn(float f) {
    union { float f; uint32_t u; } x; x.f = f;
    uint32_t r = x.u + 0x7FFFu + ((x.u >> 16) & 1u);
    return (u16)(r >> 16);
}
__device__ __forceinline__ float bf2f(u16 s) {
    union { uint32_t u; float f; } x; x.u = ((uint32_t)s) << 16;
    return x.f;
}

// ---- async global->LDS, 16B per lane ----
#define ASYNC16(gp, lp) \
    __builtin_amdgcn_global_load_lds((const __attribute__((address_space(1))) void*)(gp), \
                                     (__attribute__((address_space(3))) void*)(lp), 16, 0, 0)

// ============================================================
// Kernel 1: fp32 -> (bf16 hi, bf16 lo) split, 8 elems/thread
// ============================================================
__global__ __launch_bounds__(256) void split_kernel(const float* __restrict__ in,
                                                    u16* __restrict__ hi,
                                                    u16* __restrict__ lo,
                                                    int nvec) {   // nvec = n/8
    int i = blockIdx.x * 256 + threadIdx.x;
    if (i >= nvec) return;
    f32x4 v0 = ((const f32x4*)in)[2*i];
    f32x4 v1 = ((const f32x4*)in)[2*i + 1];
    u16x8 hv, lv;
#pragma unroll
    for (int j = 0; j < 8; ++j) {
        float f = (j < 4) ? v0[j] : v1[j - 4];
        u16 h = f2bf_rn(f);
        hv[j] = h;
        lv[j] = f2bf_rn(f - bf2f(h));
    }
    ((u16x8*)hi)[i] = hv;
    ((u16x8*)lo)[i] = lv;
}

// ============================================================
// Kernel 2: bf16x3 MFMA GEMM (NT: both operands K-major) + bias + tanh-GELU
// C[m][o] = sum_k x[m][k]*W[o][k] ; writes g = gelu(C + b) to out (fp32)
// m97 structure: 128x128 tile, BK=32, 4 waves, global_load_lds w=16
// ============================================================
__global__ __launch_bounds__(256, 2)
void gemm_gelu_kernel(const u16* __restrict__ xh, const u16* __restrict__ xl,
                      const u16* __restrict__ wh, const u16* __restrict__ wl,
                      const float* __restrict__ bias, float* __restrict__ out) {
    __shared__ __align__(16) u16 sAh[BM * BK];
    __shared__ __align__(16) u16 sAl[BM * BK];
    __shared__ __align__(16) u16 sBh[BN * BK];
    __shared__ __align__(16) u16 sBl[BN * BK];

    const int tid  = threadIdx.x;
    const int lane = tid & 63;
    const int wid  = tid >> 6;

    // XCD-aware swizzle (grid = 4096, divisible by 8 -> simple form is bijective)
    const int nwg = gridDim.x;
    const int cpx = nwg >> 3;
    const int swz = (blockIdx.x & 7) * cpx + (blockIdx.x >> 3);
    const int bm = swz >> 5;     // M tiles: 128   (consecutive swz share A-panel)
    const int bn = swz & 31;     // N tiles: 32

    const int row0 = bm * BM;
    const int col0 = bn * BN;

    // staging: chunk c in [0,512): covers LDS bytes [c*16, c*16+16)
    //   tile row = c>>2, k offset = (c&3)*8
    const int c0 = tid;
    const int c1 = 256 + tid;
    const size_t aOff0 = (size_t)(row0 + (c0 >> 2)) * K_DIM + ((c0 & 3) << 3);
    const size_t aOff1 = (size_t)(row0 + (c1 >> 2)) * K_DIM + ((c1 & 3) << 3);
    const size_t bOff0 = (size_t)(col0 + (c0 >> 2)) * K_DIM + ((c0 & 3) << 3);
    const size_t bOff1 = (size_t)(col0 + (c1 >> 2)) * K_DIM + ((c1 & 3) << 3);

    f32x4 acc[4][4] = {};
    const int wrow = (wid >> 1) << 6;   // wave output sub-tile: 64x64
    const int wcol = (wid & 1) << 6;
    const int fr = lane & 15;
    const int kq = (lane >> 4) << 3;    // 0,8,16,24

    for (int kt = 0; kt < NK; ++kt) {
        const size_t kofs = (size_t)kt * BK;
        // ---- stage hi/lo tiles of A and B (8 x 16B per thread) ----
        ASYNC16(xh + aOff0 + kofs, sAh + c0 * 8);
        ASYNC16(xh + aOff1 + kofs, sAh + c1 * 8);
        ASYNC16(xl + aOff0 + kofs, sAl + c0 * 8);
        ASYNC16(xl + aOff1 + kofs, sAl + c1 * 8);
        ASYNC16(wh + bOff0 + kofs, sBh + c0 * 8);
        ASYNC16(wh + bOff1 + kofs, sBh + c1 * 8);
        ASYNC16(wl + bOff0 + kofs, sBl + c0 * 8);
        ASYNC16(wl + bOff1 + kofs, sBl + c1 * 8);
        __syncthreads();   // compiler drains vmcnt(0) before s_barrier -> LDS ready

        // ---- fragments + 48 MFMA (3 error-compensation terms) ----
        bf16x8 bh[4], bl[4];
#pragma unroll
        for (int n = 0; n < 4; ++n) {
            const int r = wcol + n * 16 + fr;
            bh[n] = *(const bf16x8*)(sBh + r * BK + kq);
            bl[n] = *(const bf16x8*)(sBl + r * BK + kq);
        }
#pragma unroll
        for (int m = 0; m < 4; ++m) {
            const int r = wrow + m * 16 + fr;
            bf16x8 ah = *(const bf16x8*)(sAh + r * BK + kq);
            bf16x8 al = *(const bf16x8*)(sAl + r * BK + kq);
#pragma unroll
            for (int n = 0; n < 4; ++n) {
                // small terms first (better fp32 accumulation order), big term last
                acc[m][n] = __builtin_amdgcn_mfma_f32_16x16x32_bf16(al, bh[n], acc[m][n], 0, 0, 0);
                acc[m][n] = __builtin_amdgcn_mfma_f32_16x16x32_bf16(ah, bl[n], acc[m][n], 0, 0, 0);
                acc[m][n] = __builtin_amdgcn_mfma_f32_16x16x32_bf16(ah, bh[n], acc[m][n], 0, 0, 0);
            }
        }
        __syncthreads();   // protect LDS from next iteration's stage
    }

    // ---- epilogue: bias + tanh-GELU, write g to out (fp32) ----
    // C/D layout (verified m89/m91): col = lane&15, row = (lane>>4)*4 + reg
    const float SC = 0.7978845608028654f;  // sqrt(2/pi)
#pragma unroll
    for (int n = 0; n < 4; ++n) {
        const int col = col0 + wcol + n * 16 + (lane & 15);
        const float bc = bias[col];
#pragma unroll
        for (int m = 0; m < 4; ++m) {
            const int rbase = row0 + wrow + m * 16 + ((lane >> 4) << 2);
#pragma unroll
            for (int r = 0; r < 4; ++r) {
                float h = acc[m][n][r] + bc;
                float t = tanhf(SC * (h + 0.044715f * h * h * h));
                out[(size_t)(rbase + r) * N_DIM + col] = 0.5f * h * (1.0f + t);
            }
        }
    }
}

// ============================================================
// Kernel 3: in-place row LayerNorm (biased var, eps=1e-12), two-pass
// one 256-thread block per row; row held in registers (16 f32/thread)
// ============================================================
__global__ __launch_bounds__(256)
void ln_kernel(float* __restrict__ out, const float* __restrict__ a2,
               const float* __restrict__ b2) {
    const int row = blockIdx.x;
    float* g = out + (size_t)row * N_DIM;
    const int tid = threadIdx.x;

    f32x4 v[4];
    float s = 0.f;
#pragma unroll
    for (int j = 0; j < 4; ++j) {
        v[j] = ((const f32x4*)g)[j * 256 + tid];
        s += v[j][0] + v[j][1] + v[j][2] + v[j][3];
    }
#pragma unroll
    for (int o = 32; o > 0; o >>= 1) s += __shfl_xor(s, o, 64);
    __shared__ float red[4];
    if ((tid & 63) == 0) red[tid >> 6] = s;
    __syncthreads();
    s = red[0] + red[1] + red[2] + red[3];
    const float mean = s * (1.0f / N_DIM);

    float q = 0.f;
#pragma unroll
    for (int j = 0; j < 4; ++j)
#pragma unroll
        for (int e = 0; e < 4; ++e) { float d = v[j][e] - mean; q += d * d; }
#pragma unroll
    for (int o = 32; o > 0; o >>= 1) q += __shfl_xor(q, o, 64);
    __shared__ float red2[4];
    if ((tid & 63) == 0) red2[tid >> 6] = q;
    __syncthreads();
    q = red2[0] + red2[1] + red2[2] + red2[3];
    const float var = q * (1.0f / N_DIM);
    const float inv = 1.0f / sqrtf(var + 1e-12f);

#pragma unroll
    for (int j = 0; j < 4; ++j) {
        f32x4 av = ((const f32x4*)a2)[j * 256 + tid];
        f32x4 bv = ((const f32x4*)b2)[j * 256 + tid];
        f32x4 o4;
#pragma unroll
        for (int e = 0; e < 4; ++e) o4[e] = (v[j][e] - mean) * inv * av[e] + bv[e];
        ((f32x4*)g)[j * 256 + tid] = o4;
    }
}

// ============================================================
extern "C" void kernel_launch(void* const* d_in, const int* in_sizes, int n_in,
                              void* d_out, int out_size, void* d_ws, size_t ws_size,
                              hipStream_t stream) {
    const float* x  = (const float*)d_in[0];   // [16384, 4096]
    const float* W  = (const float*)d_in[1];   // [4096, 4096] (torch [out,in])
    const float* b  = (const float*)d_in[2];
    const float* a2 = (const float*)d_in[3];
    const float* b2 = (const float*)d_in[4];
    float* out = (float*)d_out;

    // workspace layout (320 MiB total):
    //   xh 128MiB | xl 128MiB | wh 32MiB | wl 32MiB
    char* ws = (char*)d_ws;
    u16* xh = (u16*)(ws);
    u16* xl = (u16*)(ws + 134217728ull);
    u16* wh = (u16*)(ws + 268435456ull);
    u16* wl = (u16*)(ws + 301989888ull);

    // split x (67.1M elems -> 8.39M vec8) and W (16.8M -> 2.1M vec8)
    split_kernel<<<8388608 / 256, 256, 0, stream>>>(x, xh, xl, 8388608);
    split_kernel<<<2097152 / 256, 256, 0, stream>>>(W, wh, wl, 2097152);

    // GEMM + bias + GELU: grid = (16384/128) * (4096/128) = 128*32 = 4096
    gemm_gelu_kernel<<<4096, 256, 0, stream>>>(xh, xl, wh, wl, b, out);

    // LayerNorm in-place: one block per row
    ln_kernel<<<M_TOTAL, 256, 0, stream>>>(out, a2, b2);
}

// Round 10
// 2411.883 us; speedup vs baseline: 1.1043x; 1.1043x over previous
//
#include <hip/hip_runtime.h>
#include <hip/hip_bf16.h>
#include <stdint.h>

// Problem constants (B=8, S=2048, H=4096)
#define M_TOTAL 16384
#define K_DIM   4096
#define N_DIM   4096
#define BM 128
#define BN 128
#define BK 32
#define NK (K_DIM / BK)   // 128 K-steps

typedef unsigned short u16;
typedef __attribute__((ext_vector_type(4))) float  f32x4;
typedef __attribute__((ext_vector_type(8))) short  bf16x8;   // 8 bf16 = 4 VGPRs (MFMA A/B frag)
typedef __attribute__((ext_vector_type(8))) unsigned short u16x8;

// ---- bf16 split helpers (round-to-nearest-even via bit trick) ----
__device__ __forceinline__ u16 f2bf_rn(float f) {
    union { float f; uint32_t u; } x; x.f = f;
    uint32_t r = x.u + 0x7FFFu + ((x.u >> 16) & 1u);
    return (u16)(r >> 16);
}
__device__ __forceinline__ float bf2f(u16 s) {
    union { uint32_t u; float f; } x; x.u = ((uint32_t)s) << 16;
    return x.f;
}

// ---- async global->LDS, 16B per lane ----
#define ASYNC16(gp, lp) \
    __builtin_amdgcn_global_load_lds((const __attribute__((address_space(1))) void*)(gp), \
                                     (__attribute__((address_space(3))) void*)(lp), 16, 0, 0)

// ============================================================
// Kernel 1: fp32 -> (bf16 hi, bf16 lo) split, 8 elems/thread
// ============================================================
__global__ __launch_bounds__(256) void split_kernel(const float* __restrict__ in,
                                                    u16* __restrict__ hi,
                                                    u16* __restrict__ lo,
                                                    int nvec) {   // nvec = n/8
    int i = blockIdx.x * 256 + threadIdx.x;
    if (i >= nvec) return;
    f32x4 v0 = ((const f32x4*)in)[2*i];
    f32x4 v1 = ((const f32x4*)in)[2*i + 1];
    u16x8 hv, lv;
#pragma unroll
    for (int j = 0; j < 8; ++j) {
        float f = (j < 4) ? v0[j] : v1[j - 4];
        u16 h = f2bf_rn(f);
        hv[j] = h;
        lv[j] = f2bf_rn(f - bf2f(h));
    }
    ((u16x8*)hi)[i] = hv;
    ((u16x8*)lo)[i] = lv;
}

// ============================================================
// Kernel 2: bf16x3 MFMA GEMM (NT) + bias + tanh-GELU
//   - 2-phase double-buffered LDS pipeline: STAGE(t+1) issued BEFORE
//     compute(t); ONE __syncthreads() per K-step (baseline had two).
//     __syncthreads() == s_waitcnt vmcnt(0) lgkmcnt(0) + s_barrier, which
//     is exactly the drain the dbuf handoff needs (compiler-guaranteed).
//   - B-hot XCD mapping: each XCD keeps 2 bn-panels (4 MiB = L2) hot
//     across the full bm sweep; same bm across XCDs -> A shared via LLC
// ============================================================
__global__ __launch_bounds__(256, 2)
void gemm_gelu_kernel(const u16* __restrict__ xh, const u16* __restrict__ xl,
                      const u16* __restrict__ wh, const u16* __restrict__ wl,
                      const float* __restrict__ bias, float* __restrict__ out) {
    __shared__ __align__(16) u16 sAh[2][BM * BK];
    __shared__ __align__(16) u16 sAl[2][BM * BK];
    __shared__ __align__(16) u16 sBh[2][BN * BK];
    __shared__ __align__(16) u16 sBl[2][BN * BK];

    const int tid  = threadIdx.x;
    const int lane = tid & 63;
    const int wid  = tid >> 6;

    // ---- B-hot XCD-aware mapping (bijective: 8 XCD x 2 rounds x 128 bm x 2 bn) ----
    const int bid = blockIdx.x;
    const int c  = bid & 7;          // XCD (round-robin dispatch)
    const int i  = bid >> 3;         // per-XCD sequence 0..511
    const int r  = i >> 8;           // round 0..1
    const int j  = i & 255;
    const int bm = j >> 1;           // 0..127: A-panel walks; shared across XCDs at same time
    const int bn = (c << 2) + (r << 1) + (j & 1);  // 2 hot B-panels per XCD per round

    const int row0 = bm * BM;
    const int col0 = bn * BN;

    // staging: chunk cc in [0,512): LDS 16B slot cc; row = cc>>2, k-slot = cc&3
    const int c0 = tid;
    const int c1 = 256 + tid;
    const size_t aOff0 = (size_t)(row0 + (c0 >> 2)) * K_DIM + ((c0 & 3) << 3);
    const size_t aOff1 = (size_t)(row0 + (c1 >> 2)) * K_DIM + ((c1 & 3) << 3);
    const size_t bOff0 = (size_t)(col0 + (c0 >> 2)) * K_DIM + ((c0 & 3) << 3);
    const size_t bOff1 = (size_t)(col0 + (c1 >> 2)) * K_DIM + ((c1 & 3) << 3);

    auto STAGE = [&](int buf, int kt) {
        const size_t kofs = (size_t)kt * BK;
        ASYNC16(xh + aOff0 + kofs, sAh[buf] + c0 * 8);
        ASYNC16(xh + aOff1 + kofs, sAh[buf] + c1 * 8);
        ASYNC16(xl + aOff0 + kofs, sAl[buf] + c0 * 8);
        ASYNC16(xl + aOff1 + kofs, sAl[buf] + c1 * 8);
        ASYNC16(wh + bOff0 + kofs, sBh[buf] + c0 * 8);
        ASYNC16(wh + bOff1 + kofs, sBh[buf] + c1 * 8);
        ASYNC16(wl + bOff0 + kofs, sBl[buf] + c0 * 8);
        ASYNC16(wl + bOff1 + kofs, sBl[buf] + c1 * 8);
    };

    f32x4 acc[4][4] = {};
    const int wrow = (wid >> 1) << 6;   // wave output sub-tile: 64x64
    const int wcol = (wid & 1) << 6;
    const int fr = lane & 15;
    const int kq = (lane >> 4) << 3;    // k-offset 0,8,16,24

    // ---- prologue: fill buffer 0 ----
    STAGE(0, 0);
    __syncthreads();

    for (int kt = 0; kt < NK; ++kt) {
        const int cur = kt & 1;
        // issue next tile's stage; its latency hides under this tile's compute
        if (kt + 1 < NK) STAGE(cur ^ 1, kt + 1);

        // ---- fragments + 48 MFMA (3 error-compensation terms) ----
        bf16x8 bh[4], bl[4];
#pragma unroll
        for (int n = 0; n < 4; ++n) {
            const int rr = wcol + n * 16 + fr;
            bh[n] = *(const bf16x8*)(sBh[cur] + rr * BK + kq);
            bl[n] = *(const bf16x8*)(sBl[cur] + rr * BK + kq);
        }
#pragma unroll
        for (int m = 0; m < 4; ++m) {
            const int rr = wrow + m * 16 + fr;
            bf16x8 ah = *(const bf16x8*)(sAh[cur] + rr * BK + kq);
            bf16x8 al = *(const bf16x8*)(sAl[cur] + rr * BK + kq);
#pragma unroll
            for (int n = 0; n < 4; ++n) {
                // small terms first (better fp32 accumulation order), big term last
                acc[m][n] = __builtin_amdgcn_mfma_f32_16x16x32_bf16(al, bh[n], acc[m][n], 0, 0, 0);
                acc[m][n] = __builtin_amdgcn_mfma_f32_16x16x32_bf16(ah, bl[n], acc[m][n], 0, 0, 0);
                acc[m][n] = __builtin_amdgcn_mfma_f32_16x16x32_bf16(ah, bh[n], acc[m][n], 0, 0, 0);
            }
        }

        // ONE sync per K-step: drains this wave's stage-writes (vmcnt) and
        // read-retires (lgkmcnt), then barriers. After it: next buffer is
        // fully staged by all waves, and buf[cur] is safe to overwrite.
        __syncthreads();
    }

    // ---- epilogue: bias + tanh-GELU, write g to out (fp32) ----
    // C/D layout (verified m89/m91): col = lane&15, row = (lane>>4)*4 + reg
    const float SC = 0.7978845608028654f;  // sqrt(2/pi)
#pragma unroll
    for (int n = 0; n < 4; ++n) {
        const int col = col0 + wcol + n * 16 + (lane & 15);
        const float bc = bias[col];
#pragma unroll
        for (int m = 0; m < 4; ++m) {
            const int rbase = row0 + wrow + m * 16 + ((lane >> 4) << 2);
#pragma unroll
            for (int rr = 0; rr < 4; ++rr) {
                float h = acc[m][n][rr] + bc;
                float t = tanhf(SC * (h + 0.044715f * h * h * h));
                out[(size_t)(rbase + rr) * N_DIM + col] = 0.5f * h * (1.0f + t);
            }
        }
    }
}

// ============================================================
// Kernel 3: in-place row LayerNorm (biased var, eps=1e-12), two-pass
// ============================================================
__global__ __launch_bounds__(256)
void ln_kernel(float* __restrict__ out, const float* __restrict__ a2,
               const float* __restrict__ b2) {
    const int row = blockIdx.x;
    float* g = out + (size_t)row * N_DIM;
    const int tid = threadIdx.x;

    f32x4 v[4];
    float s = 0.f;
#pragma unroll
    for (int j = 0; j < 4; ++j) {
        v[j] = ((const f32x4*)g)[j * 256 + tid];
        s += v[j][0] + v[j][1] + v[j][2] + v[j][3];
    }
#pragma unroll
    for (int o = 32; o > 0; o >>= 1) s += __shfl_xor(s, o, 64);
    __shared__ float red[4];
    if ((tid & 63) == 0) red[tid >> 6] = s;
    __syncthreads();
    s = red[0] + red[1] + red[2] + red[3];
    const float mean = s * (1.0f / N_DIM);

    float q = 0.f;
#pragma unroll
    for (int j = 0; j < 4; ++j)
#pragma unroll
        for (int e = 0; e < 4; ++e) { float d = v[j][e] - mean; q += d * d; }
#pragma unroll
    for (int o = 32; o > 0; o >>= 1) q += __shfl_xor(q, o, 64);
    __shared__ float red2[4];
    if ((tid & 63) == 0) red2[tid >> 6] = q;
    __syncthreads();
    q = red2[0] + red2[1] + red2[2] + red2[3];
    const float var = q * (1.0f / N_DIM);
    const float inv = 1.0f / sqrtf(var + 1e-12f);

#pragma unroll
    for (int j = 0; j < 4; ++j) {
        f32x4 av = ((const f32x4*)a2)[j * 256 + tid];
        f32x4 bv = ((const f32x4*)b2)[j * 256 + tid];
        f32x4 o4;
#pragma unroll
        for (int e = 0; e < 4; ++e) o4[e] = (v[j][e] - mean) * inv * av[e] + bv[e];
        ((f32x4*)g)[j * 256 + tid] = o4;
    }
}

// ============================================================
extern "C" void kernel_launch(void* const* d_in, const int* in_sizes, int n_in,
                              void* d_out, int out_size, void* d_ws, size_t ws_size,
                              hipStream_t stream) {
    const float* x  = (const float*)d_in[0];   // [16384, 4096]
    const float* W  = (const float*)d_in[1];   // [4096, 4096] (torch [out,in])
    const float* b  = (const float*)d_in[2];
    const float* a2 = (const float*)d_in[3];
    const float* b2 = (const float*)d_in[4];
    float* out = (float*)d_out;

    // workspace layout (320 MiB total): xh 128MiB | xl 128MiB | wh 32MiB | wl 32MiB
    char* ws = (char*)d_ws;
    u16* xh = (u16*)(ws);
    u16* xl = (u16*)(ws + 134217728ull);
    u16* wh = (u16*)(ws + 268435456ull);
    u16* wl = (u16*)(ws + 301989888ull);

    split_kernel<<<8388608 / 256, 256, 0, stream>>>(x, xh, xl, 8388608);
    split_kernel<<<2097152 / 256, 256, 0, stream>>>(W, wh, wl, 2097152);

    // GEMM + bias + GELU: grid = 128 bm * 32 bn = 4096
    gemm_gelu_kernel<<<4096, 256, 0, stream>>>(xh, xl, wh, wl, b, out);

    // LayerNorm in-place: one block per row
    ln_kernel<<<M_TOTAL, 256, 0, stream>>>(out, a2, b2);
}